// Round 1
// baseline (25827.835 us; speedup 1.0000x reference)
//
#include <hip/hip_runtime.h>

// MassConservingLSTM on MI355X.
// Strategy: 1 kernel launch per time step (stream order = grid barrier).
// Kernel t: [finalize step t-1 -> build g_t in LDS] then [GEMM+softmax+contraction for step t].
// Weights converted once to bf16 (log2e folded in), per-step GEMM via 16x16x32 bf16 MFMA.
// c_new accumulated across WGs via f32 atomics into a triple-buffered accumulator.

#define LSTEPS 1024
#define LOG2E 1.4426950408889634f

typedef unsigned short u16;
typedef unsigned int u32;
typedef __attribute__((ext_vector_type(8))) short s8v;   // 8 x bf16 (MFMA A/B frag)
typedef __attribute__((ext_vector_type(4))) float f4v;   // MFMA C/D frag

__device__ __forceinline__ u16 f2bf(float f) {
  u32 u = __float_as_uint(f);
  u += 0x7fffu + ((u >> 16) & 1u);   // RNE (inputs finite)
  return (u16)(u >> 16);
}
__device__ __forceinline__ float bf2f(u16 h) { return __uint_as_float(((u32)h) << 16); }

// ---------------- weight conversion: f32 -> bf16, fold log2e ----------------
__global__ __launch_bounds__(256) void convert_w_kernel(
    const float* __restrict__ Wr, const float* __restrict__ Wi, const float* __restrict__ Wo,
    u16* __restrict__ WrB, u16* __restrict__ WiB, u16* __restrict__ WoB) {
  const int n1 = 16384 * 160, n2 = 8192 * 160, n3 = 128 * 160;
  int idx = blockIdx.x * blockDim.x + threadIdx.x;
  const int stride = gridDim.x * blockDim.x;
  for (; idx < n1 + n2 + n3; idx += stride) {
    if (idx < n1)            WrB[idx]           = f2bf(Wr[idx] * LOG2E);
    else if (idx < n1 + n2)  WiB[idx - n1]      = f2bf(Wi[idx - n1] * LOG2E);
    else                     WoB[idx - n1 - n2] = f2bf(Wo[idx - n1 - n2] * (-LOG2E)); // sigmoid via exp2(-x*log2e)
  }
}

// ---------------- per-step kernel ----------------
// grid 256 WGs x 512 threads. WG decode: wg = oslot*32 + btile*8 + xcd.
//   btile (0..3): which 64-batch tile. orow0 = xcd*24 + oslot*3: this WG's 3 softmax-row-blocks
//   (orow < 128 -> r-matrix row o=orow; else i-matrix row i=orow-128).
// Waves: 2x4 grid over the 64b x 128p task tile: wave = 32b x 32p.
__global__ __launch_bounds__(512, 2) void step_kernel(
    const float* __restrict__ xm, const float* __restrict__ xa,
    const float* __restrict__ br, const float* __restrict__ bi, const float* __restrict__ bo,
    const u16* __restrict__ WrB, const u16* __restrict__ WiB, const u16* __restrict__ WoB,
    float* __restrict__ c_acc,   // [3][256*128] triple-buffered c_new accumulator
    float* __restrict__ o_buf,   // [2][256*128] o-gate logits (pre-scaled by -log2e)
    float* __restrict__ hs_out, float* __restrict__ cs_out, int t) {
  // W tile padded to 168 bf16/row: rows 16B aligned, ~2-way bank conflicts (free).
  // cols 160..167 are pad "holes" reused as the cross-wave Z-exchange buffer.
  __shared__ u16 W_lds[128][168];
  __shared__ u16 g_lds[64][160];

  const int tid = threadIdx.x;
  const int wg = blockIdx.x;
  const int xcd = wg & 7;
  const int l32 = wg >> 3;
  const int btile = l32 & 3;
  const int oslot = l32 >> 2;
  const int rank = oslot * 8 + xcd;        // unique in [0,64) within this btile
  const int orow0 = xcd * 24 + oslot * 3;  // 3 consecutive row-blocks

  const int lane = tid & 63;
  const int wv = tid >> 6;   // wave 0..7
  const int wm = wv >> 2;    // b-half 0..1
  const int wn = wv & 3;     // p-quarter 0..3
  const int lg = lane >> 4;  // 16-lane group 0..3
  const int lc = lane & 15;

  // zero c_acc buffer for step t+1 (its last readers finished in kernel t-1)
  if (t < LSTEPS && tid < 32) {
    float4* zb = (float4*)(c_acc + ((t + 1) % 3) * 32768 + wg * 128);
    zb[tid] = make_float4(0.f, 0.f, 0.f, 0.f);
  }

  // ---------- finalize step t-1; build g_t (bf16) in LDS ----------
  const int bloc = tid >> 3;      // 0..63 batch row in tile
  const int seg = tid & 7;        // 16-elem column segment
  const int pseg = seg * 16;
  const int bg = btile * 64 + bloc;

  if (t > 0) {
    const float* ca = c_acc + ((t + 2) % 3) * 32768 + bg * 128 + pseg;  // (t-1)%3
    const float* ol = o_buf + ((t + 1) & 1) * 32768 + bg * 128 + pseg;  // (t-1)&1
    float hv[16], cc[16];
    float csum = 0.f;
#pragma unroll
    for (int q = 0; q < 4; ++q) {
      float4 cn = ((const float4*)ca)[q];
      float4 sl = ((const float4*)ol)[q];
      float cna[4] = {cn.x, cn.y, cn.z, cn.w};
      float sla[4] = {sl.x, sl.y, sl.z, sl.w};
#pragma unroll
      for (int j = 0; j < 4; ++j) {
        float e2 = __builtin_amdgcn_exp2f(sla[j]);       // = exp(-x)
        float og = __builtin_amdgcn_rcpf(1.f + e2);      // sigmoid
        float h = og * cna[j];
        float c2 = cna[j] - h;
        hv[q * 4 + j] = h;
        cc[q * 4 + j] = c2;
        csum += c2;
      }
    }
    csum += __shfl_xor(csum, 1);
    csum += __shfl_xor(csum, 2);
    csum += __shfl_xor(csum, 4);
    float sc = (csum == 0.f) ? 1.f : csum;
    float inv = __builtin_amdgcn_rcpf(sc);
    if (bloc == rank) {  // each WG writes one batch row of the outputs
      float* ho = hs_out + ((size_t)(t - 1) * 256 + bg) * 128 + pseg;
      float* co = cs_out + ((size_t)(t - 1) * 256 + bg) * 128 + pseg;
#pragma unroll
      for (int q = 0; q < 4; ++q) {
        ((float4*)ho)[q] = make_float4(hv[q * 4], hv[q * 4 + 1], hv[q * 4 + 2], hv[q * 4 + 3]);
        ((float4*)co)[q] = make_float4(cc[q * 4], cc[q * 4 + 1], cc[q * 4 + 2], cc[q * 4 + 3]);
      }
    }
    u32 w[8];
#pragma unroll
    for (int k = 0; k < 8; ++k)
      w[k] = (u32)f2bf(cc[2 * k] * inv) | ((u32)f2bf(cc[2 * k + 1] * inv) << 16);
    uint4* gdst = (uint4*)&g_lds[bloc][32 + pseg];
    gdst[0] = make_uint4(w[0], w[1], w[2], w[3]);
    gdst[1] = make_uint4(w[4], w[5], w[6], w[7]);
  } else {
    uint4* gdst = (uint4*)&g_lds[bloc][32 + pseg];
    gdst[0] = make_uint4(0, 0, 0, 0);
    gdst[1] = make_uint4(0, 0, 0, 0);
  }

  if (t == LSTEPS) return;  // tail launch: finalize only

  {  // xa -> g_lds[:, 0..31]
    float4 xv = ((const float4*)(xa + ((size_t)t * 256 + bg) * 32))[seg];
    uint2 pk = make_uint2((u32)f2bf(xv.x) | ((u32)f2bf(xv.y) << 16),
                          (u32)f2bf(xv.z) | ((u32)f2bf(xv.w) << 16));
    *(uint2*)&g_lds[bloc][seg * 4] = pk;
  }
  __syncthreads();

  // ---------- A fragments (g) pinned in registers for all 3 tasks ----------
  // A layout (16x16x32): row = lane&15, k = 8*(lane>>4) + j
  s8v afr[2][5];
#pragma unroll
  for (int mt = 0; mt < 2; ++mt)
#pragma unroll
    for (int ks = 0; ks < 5; ++ks)
      afr[mt][ks] = *(const s8v*)&g_lds[wm * 32 + mt * 16 + lc][ks * 32 + lg * 8];

  float cpart[2][2][4] = {};  // local c_new partial over this WG's 3 rows

  const float* cprev = c_acc + ((t + 2) % 3) * 32768;
  const float* oprev = o_buf + ((t + 1) & 1) * 32768;

  // ---------- stage W for task 0 ----------
  uint4 pf[5];
  {
    const u16* wb = (orow0 < 128) ? (WrB + (size_t)orow0 * 20480)
                                  : (WiB + (size_t)(orow0 - 128) * 20480);
#pragma unroll
    for (int i = 0; i < 5; ++i) pf[i] = ((const uint4*)wb)[tid + i * 512];
  }
#pragma unroll
  for (int i = 0; i < 5; ++i) {
    int chunk = tid + i * 512;  // 16B chunks: 20 per row of 160 bf16
    *(uint4*)((char*)&W_lds[0][0] + (chunk / 20) * 336 + (chunk % 20) * 16) = pf[i];
  }
  __syncthreads();

  for (int task = 0; task < 3; ++task) {
    const int orow = orow0 + task;
    const bool is_r = (orow < 128);
    if (task < 2) {  // prefetch next W block into registers (hides under MFMA)
      const int nr = orow + 1;
      const u16* wb = (nr < 128) ? (WrB + (size_t)nr * 20480)
                                 : (WiB + (size_t)(nr - 128) * 20480);
#pragma unroll
      for (int i = 0; i < 5; ++i) pf[i] = ((const uint4*)wb)[tid + i * 512];
    }
    // bias folded into accumulator init (already need *log2e)
    const float* bptr = is_r ? (br + orow * 128) : (bi + (orow - 128) * 128);
    float bias0 = bptr[wn * 32 + lc] * LOG2E;
    float bias1 = bptr[wn * 32 + 16 + lc] * LOG2E;
    f4v acc[2][2];
#pragma unroll
    for (int mt = 0; mt < 2; ++mt) {
      acc[mt][0] = (f4v){bias0, bias0, bias0, bias0};
      acc[mt][1] = (f4v){bias1, bias1, bias1, bias1};
    }
    // B layout: col = lane&15 (= W row p), k = 8*(lane>>4)+j -> contiguous in W_lds row
#pragma unroll
    for (int ks = 0; ks < 5; ++ks) {
      s8v b0 = *(const s8v*)&W_lds[wn * 32 + lc][ks * 32 + lg * 8];
      s8v b1 = *(const s8v*)&W_lds[wn * 32 + 16 + lc][ks * 32 + lg * 8];
      acc[0][0] = __builtin_amdgcn_mfma_f32_16x16x32_bf16(afr[0][ks], b0, acc[0][0], 0, 0, 0);
      acc[1][0] = __builtin_amdgcn_mfma_f32_16x16x32_bf16(afr[1][ks], b0, acc[1][0], 0, 0, 0);
      acc[0][1] = __builtin_amdgcn_mfma_f32_16x16x32_bf16(afr[0][ks], b1, acc[0][1], 0, 0, 0);
      acc[1][1] = __builtin_amdgcn_mfma_f32_16x16x32_bf16(afr[1][ks], b1, acc[1][1], 0, 0, 0);
    }
    // softmax numerators (logits already in log2 domain); row sums
    float ev[2][2][4];
    float zp[2][4];
#pragma unroll
    for (int mt = 0; mt < 2; ++mt)
#pragma unroll
      for (int r = 0; r < 4; ++r) {
        float e0 = __builtin_amdgcn_exp2f(acc[mt][0][r]);
        float e1 = __builtin_amdgcn_exp2f(acc[mt][1][r]);
        ev[mt][0][r] = e0;
        ev[mt][1][r] = e1;
        zp[mt][r] = e0 + e1;
      }
#pragma unroll
    for (int mt = 0; mt < 2; ++mt)
#pragma unroll
      for (int r = 0; r < 4; ++r) {
        float z = zp[mt][r];
        z += __shfl_xor(z, 1);
        z += __shfl_xor(z, 2);
        z += __shfl_xor(z, 4);
        z += __shfl_xor(z, 8);
        zp[mt][r] = z;  // 32-col partial, replicated over 16-lane group
      }
    // cross-wave (4 p-quarters) Z exchange through the W_lds pad holes
    if (lc == 0) {
#pragma unroll
      for (int mt = 0; mt < 2; ++mt)
        *(float4*)((char*)&W_lds[0][0] + ((wm * 4 + wn) * 8 + mt * 4 + lg) * 336 + 320) =
            make_float4(zp[mt][0], zp[mt][1], zp[mt][2], zp[mt][3]);
    }
    __syncthreads();
#pragma unroll
    for (int mt = 0; mt < 2; ++mt) {
      float Z[4] = {0.f, 0.f, 0.f, 0.f};
#pragma unroll
      for (int w2 = 0; w2 < 4; ++w2) {
        float4 v = *(const float4*)((char*)&W_lds[0][0] + ((wm * 4 + w2) * 8 + mt * 4 + lg) * 336 + 320);
        Z[0] += v.x; Z[1] += v.y; Z[2] += v.z; Z[3] += v.w;
      }
#pragma unroll
      for (int r = 0; r < 4; ++r) {
        const int brow = wm * 32 + mt * 16 + lg * 4 + r;
        const int bg2 = btile * 64 + brow;
        float cv;
        if (is_r) {
          if (t > 0) {  // fp32-exact c[b,o] = c_new*(1-o), recomputed from fp32 buffers
            float cn = cprev[bg2 * 128 + orow];
            float s2 = oprev[bg2 * 128 + orow];
            float e2 = __builtin_amdgcn_exp2f(s2);
            cv = cn * e2 * __builtin_amdgcn_rcpf(1.f + e2);
          } else cv = 0.f;
        } else {
          cv = xm[((size_t)t * 256 + bg2) * 64 + (orow - 128)];
        }
        float coef = cv * __builtin_amdgcn_rcpf(Z[r]);
        cpart[mt][0][r] += coef * ev[mt][0][r];
        cpart[mt][1][r] += coef * ev[mt][1][r];
      }
    }
    if (task < 2) {  // write prefetched W (real cols only; holes untouched)
#pragma unroll
      for (int i = 0; i < 5; ++i) {
        int chunk = tid + i * 512;
        *(uint4*)((char*)&W_lds[0][0] + (chunk / 20) * 336 + (chunk % 20) * 16) = pf[i];
      }
      __syncthreads();
    }
  }

  // ---------- o-gate logits for step t (16 duty WGs, waves 0 & 4 reuse their A frags) ----------
  if (oslot < 4 && xcd == ((oslot + 2 * btile) & 7) && wn == 0) {
    const int qoff = oslot * 32;
    float ob0 = bo[qoff + lc] * (-LOG2E);
    float ob1 = bo[qoff + 16 + lc] * (-LOG2E);
    f4v oacc[2][2];
#pragma unroll
    for (int mt = 0; mt < 2; ++mt) {
      oacc[mt][0] = (f4v){ob0, ob0, ob0, ob0};
      oacc[mt][1] = (f4v){ob1, ob1, ob1, ob1};
    }
#pragma unroll
    for (int ks = 0; ks < 5; ++ks) {  // W_o B-frags direct from global (L2-hot, 64B segments)
      s8v b0 = *(const s8v*)(WoB + (size_t)(qoff + lc) * 160 + ks * 32 + lg * 8);
      s8v b1 = *(const s8v*)(WoB + (size_t)(qoff + 16 + lc) * 160 + ks * 32 + lg * 8);
      oacc[0][0] = __builtin_amdgcn_mfma_f32_16x16x32_bf16(afr[0][ks], b0, oacc[0][0], 0, 0, 0);
      oacc[1][0] = __builtin_amdgcn_mfma_f32_16x16x32_bf16(afr[1][ks], b0, oacc[1][0], 0, 0, 0);
      oacc[0][1] = __builtin_amdgcn_mfma_f32_16x16x32_bf16(afr[0][ks], b1, oacc[0][1], 0, 0, 0);
      oacc[1][1] = __builtin_amdgcn_mfma_f32_16x16x32_bf16(afr[1][ks], b1, oacc[1][1], 0, 0, 0);
    }
    float* ob = o_buf + (t & 1) * 32768;
#pragma unroll
    for (int mt = 0; mt < 2; ++mt)
#pragma unroll
      for (int nt = 0; nt < 2; ++nt)
#pragma unroll
        for (int r = 0; r < 4; ++r)
          ob[(btile * 64 + wm * 32 + mt * 16 + lg * 4 + r) * 128 + qoff + nt * 16 + lc] = oacc[mt][nt][r];
  }

  // ---------- accumulate partial c_new (one atomic pass per step) ----------
  float* cb = c_acc + (t % 3) * 32768;
#pragma unroll
  for (int mt = 0; mt < 2; ++mt)
#pragma unroll
    for (int nt = 0; nt < 2; ++nt)
#pragma unroll
      for (int r = 0; r < 4; ++r)
        unsafeAtomicAdd(&cb[(btile * 64 + wm * 32 + mt * 16 + lg * 4 + r) * 128 + wn * 32 + nt * 16 + lc],
                        cpart[mt][nt][r]);
}

extern "C" void kernel_launch(void* const* d_in, const int* in_sizes, int n_in,
                              void* d_out, int out_size, void* d_ws, size_t ws_size,
                              hipStream_t stream) {
  const float* xm = (const float*)d_in[0];
  const float* xa = (const float*)d_in[1];
  const float* Wr = (const float*)d_in[2];
  const float* br = (const float*)d_in[3];
  const float* Wi = (const float*)d_in[4];
  const float* bi = (const float*)d_in[5];
  const float* Wo = (const float*)d_in[6];
  const float* bo = (const float*)d_in[7];

  // workspace layout (8,560,640 bytes total)
  if (ws_size < 8560640) return;
  u16* WrB = (u16*)d_ws;
  u16* WiB = WrB + 16384 * 160;
  u16* WoB = WiB + 8192 * 160;
  float* c_acc = (float*)(WoB + 128 * 160);
  float* o_buf = c_acc + 3 * 32768;

  float* hs = (float*)d_out;
  float* cs = hs + (size_t)LSTEPS * 256 * 128;

  convert_w_kernel<<<dim3(1024), dim3(256), 0, stream>>>(Wr, Wi, Wo, WrB, WiB, WoB);
  hipMemsetAsync(c_acc, 0, 3 * 32768 * sizeof(float), stream);
  for (int t = 0; t <= LSTEPS; ++t)
    step_kernel<<<dim3(256), dim3(512), 0, stream>>>(xm, xa, br, bi, bo, WrB, WiB, WoB,
                                                     c_acc, o_buf, hs, cs, t);
}